// Round 3
// baseline (733.287 us; speedup 1.0000x reference)
//
#include <hip/hip_runtime.h>
#include <hip/hip_bf16.h>

typedef __bf16 bf16;
typedef bf16 bf16x4 __attribute__((ext_vector_type(4)));
typedef bf16 bf16x8 __attribute__((ext_vector_type(8)));
typedef float f32x4 __attribute__((ext_vector_type(4)));

#define MFMA16(a, b, c) __builtin_amdgcn_mfma_f32_16x16x32_bf16((a), (b), (c), 0, 0, 0)

constexpr int kN = 49, kC = 256;
constexpr float kScale = 0.17677669529663687f;  // 1/sqrt(32)

// ---- workspace offsets (bytes) ----
constexpr int WQKV_OFF = 0;        // bf16[768*256]
constexpr int WPROJ_OFF = 393216;  // bf16[256*256]
constexpr int BIAS_OFF = 524288;   // f32[8*49*49]
constexpr int BQKV_OFF = 601120;   // f32[768]

// ---- LDS offsets (bytes) ----
constexpr int XB_OFF = 0;        // bf16 [32 cc][64 n][8] xor-swizzled (x, later attn-out)
constexpr int QK_OFF = 32768;    // bf16 [64 oc][56 n][8] (Q o<256 scaled, K 256..511)
constexpr int VT_OFF = 90112;    // bf16 [8 h][8 mc][32 d][8]  (V transposed)
constexpr int PT_OFF = 32768;    // overlay on QK(+VT head0/1): 16 waves x 4096 B
constexpr int LDS_BYTES = 122880;

// xb element-index swizzle: xor n-low bits with chunk (breaks 1024B-stride banking)
__device__ __forceinline__ int xbsw(int e) { return e ^ (((e >> 9) & 7) << 3); }

__global__ void prep_kernel(const float* __restrict__ w_qkv, const float* __restrict__ b_qkv,
                            const float* __restrict__ w_proj, const float* __restrict__ bias_table,
                            const int* __restrict__ rel_index, char* __restrict__ ws) {
  int i = blockIdx.x * 256 + threadIdx.x;
  bf16* wqkvb = (bf16*)(ws + WQKV_OFF);
  bf16* wprojb = (bf16*)(ws + WPROJ_OFF);
  float* biasx = (float*)(ws + BIAS_OFF);
  float* bqs = (float*)(ws + BQKV_OFF);
  if (i < 196608) {
    float v = w_qkv[i];
    if (i < 65536) v *= kScale;  // q rows (o<256): fold scale
    wqkvb[i] = (bf16)v;
  } else if (i < 262144) {
    int j = i - 196608;
    wprojb[j] = (bf16)w_proj[j];
  } else if (i < 281352) {
    int j = i - 262144;  // 8*2401
    int h = j / 2401, nm = j - h * 2401;
    biasx[j] = bias_table[rel_index[nm] * 8 + h];
  } else if (i < 282120) {
    int j = i - 281352;
    bqs[j] = b_qkv[j] * (j < 256 ? kScale : 1.0f);
  }
}

__global__ __launch_bounds__(1024) void attn_kernel(
    const float* __restrict__ x, const float* __restrict__ mask, const float* __restrict__ b_proj,
    const char* __restrict__ ws, float* __restrict__ out) {
  extern __shared__ char smem[];
  bf16* xb = (bf16*)(smem + XB_OFF);
  bf16* qk = (bf16*)(smem + QK_OFF);
  bf16* vt = (bf16*)(smem + VT_OFF);

  const bf16* wqkvb = (const bf16*)(ws + WQKV_OFF);
  const bf16* wprojb = (const bf16*)(ws + WPROJ_OFF);
  const float* biasx = (const float*)(ws + BIAS_OFF);
  const float* bqs = (const float*)(ws + BQKV_OFF);

  const int tid = threadIdx.x;
  const int w = blockIdx.x;
  const int lane = tid & 63;
  const int wave = tid >> 6;   // 0..15
  const int g = lane >> 4;     // 16-lane group
  const int c = lane & 15;

  const float* xw = x + (size_t)w * (kN * kC);

  // ---- stage x -> xb bf16, chunked [cc=ch/8][n][ch&7] swizzled; zero rows 49..63 ----
#pragma unroll
  for (int it = 0; it < 4; ++it) {
    int idx = it * 1024 + tid;  // over 49*64 float4 units
    if (idx < 3136) {
      int n = idx >> 6, c4 = (idx & 63) << 2;
      float4 v = ((const float4*)xw)[idx];
      bf16x4 b4;
      b4[0] = (bf16)v.x; b4[1] = (bf16)v.y; b4[2] = (bf16)v.z; b4[3] = (bf16)v.w;
      *(bf16x4*)(xb + xbsw((c4 >> 3) * 512 + n * 8 + (c4 & 7))) = b4;
    }
  }
  {
    int idx = tid;
    if (idx < 960) {
      int n = 49 + (idx >> 6), c4 = (idx & 63) << 2;
      bf16x4 z = {};
      *(bf16x4*)(xb + xbsw((c4 >> 3) * 512 + n * 8 + (c4 & 7))) = z;
    }
  }
  __syncthreads();

  // ---- sub-GEMM1: Q,K.  D[o][n] = sum_c W[o][c]*X[n][c].  2 o-tiles per wave ----
  for (int t = 0; t < 2; ++t) {
    int ot = wave * 2 + t;
    const bf16* ab = wqkvb + (ot * 16 + c) * 256 + g * 8;  // A row o = l&15, k contig
    bf16x8 afr[8];
#pragma unroll
    for (int ks = 0; ks < 8; ++ks) afr[ks] = *(const bf16x8*)(ab + ks * 32);
    f32x4 acc[4] = {};
#pragma unroll
    for (int ks = 0; ks < 8; ++ks) {
      int be = (ks * 4 + g) * 512 + c * 8;
#pragma unroll
      for (int nt = 0; nt < 4; ++nt) {
        bf16x8 bfr = *(const bf16x8*)(xb + xbsw(be + nt * 128));
        acc[nt] = MFMA16(afr[ks], bfr, acc[nt]);
      }
    }
    int ob = ot * 16 + g * 4;
    float bq0 = bqs[ob], bq1 = bqs[ob + 1], bq2 = bqs[ob + 2], bq3 = bqs[ob + 3];
    int oc = ob >> 3, olow = ob & 7;
#pragma unroll
    for (int nt = 0; nt < 4; ++nt) {
      int n = nt * 16 + c;
      if (n < 56) {
        bool ok = (n < 49);
        bf16x4 pk;
        pk[0] = ok ? (bf16)(acc[nt][0] + bq0) : (bf16)0.f;
        pk[1] = ok ? (bf16)(acc[nt][1] + bq1) : (bf16)0.f;
        pk[2] = ok ? (bf16)(acc[nt][2] + bq2) : (bf16)0.f;
        pk[3] = ok ? (bf16)(acc[nt][3] + bq3) : (bf16)0.f;
        *(bf16x4*)(qk + (oc * 448 + n * 8 + olow)) = pk;
      }
    }
  }

  // ---- sub-GEMM2: V.  D[n][o] -> vt[h][m/8][d][m&7].  1 tile per wave ----
  {
    int ct = wave;
    int o = 512 + ct * 16 + c;
    const bf16* bb = wqkvb + o * 256 + g * 8;
    bf16x8 bfr[8];
#pragma unroll
    for (int ks = 0; ks < 8; ++ks) bfr[ks] = *(const bf16x8*)(bb + ks * 32);
    f32x4 acc[4] = {};
#pragma unroll
    for (int ks = 0; ks < 8; ++ks) {
      int ae = (ks * 4 + g) * 512 + c * 8;
#pragma unroll
      for (int mt = 0; mt < 4; ++mt) {
        bf16x8 afr = *(const bf16x8*)(xb + xbsw(ae + mt * 128));
        acc[mt] = MFMA16(afr, bfr[ks], acc[mt]);
      }
    }
    float bv = bqs[o];
    int h = ct >> 1;
    int d = (ct * 16 + c) & 31;
#pragma unroll
    for (int mt = 0; mt < 4; ++mt) {
      int mb = mt * 16 + g * 4;
      bf16x4 pk;
      pk[0] = (bf16)(acc[mt][0] + bv); pk[1] = (bf16)(acc[mt][1] + bv);
      pk[2] = (bf16)(acc[mt][2] + bv); pk[3] = (bf16)(acc[mt][3] + bv);
      *(bf16x4*)(vt + (h * 2048 + (mb >> 3) * 256 + d * 8 + (mb & 7))) = pk;
    }
  }
  __syncthreads();

  // ---- attention: wave -> head h = wave/2, row-half rh = wave&1 ----
  const int h = wave >> 1, rh = wave & 1;
  bf16* ptp = (bf16*)(smem + PT_OFF + wave * 4096);  // [2 rt][16 nlow][64 m] swizzled
  const float* mk = mask + (size_t)w * 2401;
  const float* bh = biasx + h * 2401;

  // fragment preloads (all QK/VT reads happen BEFORE the overlay barrier)
  bf16x8 qa[2], kb[4], va[2][2];
#pragma unroll
  for (int r = 0; r < 2; ++r)
    qa[r] = *(const bf16x8*)(qk + ((h * 4 + g) * 448 + ((rh * 2 + r) * 16 + c) * 8));
#pragma unroll
  for (int mt = 0; mt < 4; ++mt)
    kb[mt] = *(const bf16x8*)(qk + ((32 + h * 4 + g) * 448 + (mt * 16 + c) * 8));
#pragma unroll
  for (int dt = 0; dt < 2; ++dt)
#pragma unroll
    for (int ks = 0; ks < 2; ++ks)
      va[dt][ks] = *(const bf16x8*)(vt + (h * 2048 + (ks * 4 + g) * 256 + (dt * 16 + c) * 8));
  __syncthreads();  // frags in regs; QK/VT now dead -> PT overlay is safe

  // QK^T: S[n][m] for this wave's 32 rows
  f32x4 s[2][4] = {};
#pragma unroll
  for (int r = 0; r < 2; ++r)
#pragma unroll
    for (int mt = 0; mt < 4; ++mt) s[r][mt] = MFMA16(qa[r], kb[mt], s[r][mt]);

#pragma unroll
  for (int r = 0; r < 2; ++r) {
    int rtg = rh * 2 + r;
    float pk_[4][4];  // [mt][i]
#pragma unroll
    for (int i = 0; i < 4; ++i) {
      int n = rtg * 16 + g * 4 + i;
      bool nok = (n < 49);
      float vals[4];
#pragma unroll
      for (int mt = 0; mt < 4; ++mt) {
        int m = mt * 16 + c;
        float v = -1e30f;
        if (nok && m < 49) v = s[r][mt][i] + bh[n * 49 + m] + mk[n * 49 + m];
        vals[mt] = v;
      }
      float mx = fmaxf(fmaxf(vals[0], vals[1]), fmaxf(vals[2], vals[3]));
      mx = fmaxf(mx, __shfl_xor(mx, 1));
      mx = fmaxf(mx, __shfl_xor(mx, 2));
      mx = fmaxf(mx, __shfl_xor(mx, 4));
      mx = fmaxf(mx, __shfl_xor(mx, 8));
      float p0 = __expf(vals[0] - mx), p1 = __expf(vals[1] - mx);
      float p2 = __expf(vals[2] - mx), p3 = __expf(vals[3] - mx);
      float sum = p0 + p1 + p2 + p3;
      sum += __shfl_xor(sum, 1);
      sum += __shfl_xor(sum, 2);
      sum += __shfl_xor(sum, 4);
      sum += __shfl_xor(sum, 8);
      float rinv = 1.0f / sum;
      pk_[0][i] = p0 * rinv; pk_[1][i] = p1 * rinv;
      pk_[2][i] = p2 * rinv; pk_[3][i] = p3 * rinv;
    }
    // store P[n][m] swizzled: elem = r*1024 + nl*64 + (m ^ (g<<4) ^ ((i&1)<<3))
#pragma unroll
    for (int mt = 0; mt < 4; ++mt) {
      int m = mt * 16 + c;
#pragma unroll
      for (int i = 0; i < 4; ++i) {
        int nl = g * 4 + i;
        ptp[r * 1024 + nl * 64 + (m ^ (g << 4) ^ ((i & 1) << 3))] = (bf16)pk_[mt][i];
      }
    }
  }
  asm volatile("s_waitcnt lgkmcnt(0)" ::: "memory");  // own-wave P visible

  // PV^T: out^T[d][n] = sum_m V^T[d][m] * P^T[m][n]  (this wave's 32 n-cols)
  f32x4 oacc[2][2] = {};
  const int xr = ((c >> 2) << 4) ^ ((c & 1) << 3);
#pragma unroll
  for (int ntl = 0; ntl < 2; ++ntl) {
    const bf16* pr = ptp + ntl * 1024 + c * 64;
    bf16x8 pb0 = *(const bf16x8*)(pr + ((g * 8) ^ xr));
    bf16x8 pb1 = *(const bf16x8*)(pr + ((32 + g * 8) ^ xr));
#pragma unroll
    for (int dt = 0; dt < 2; ++dt) {
      oacc[dt][ntl] = MFMA16(va[dt][0], pb0, oacc[dt][ntl]);
      oacc[dt][ntl] = MFMA16(va[dt][1], pb1, oacc[dt][ntl]);
    }
  }
  // attn-out -> xb (xb frag reads all completed before attn barrier)
#pragma unroll
  for (int dt = 0; dt < 2; ++dt) {
    int cb = h * 32 + dt * 16 + g * 4;
    int cc = cb >> 3, clow = cb & 7;
#pragma unroll
    for (int ntl = 0; ntl < 2; ++ntl) {
      int n = rh * 32 + ntl * 16 + c;
      bf16x4 pk;
      pk[0] = (bf16)oacc[dt][ntl][0]; pk[1] = (bf16)oacc[dt][ntl][1];
      pk[2] = (bf16)oacc[dt][ntl][2]; pk[3] = (bf16)oacc[dt][ntl][3];
      *(bf16x4*)(xb + xbsw(cc * 512 + n * 8 + clow)) = pk;
    }
  }
  __syncthreads();

  // ---- proj: out[n][co] = sum_c ao[n][c]*Wp[co][c] + bp.  1 tile per wave ----
  float* outw = out + (size_t)w * (kN * kC);
  {
    int ct = wave;
    const bf16* bb = wprojb + (ct * 16 + c) * 256 + g * 8;
    bf16x8 bfr[8];
#pragma unroll
    for (int ks = 0; ks < 8; ++ks) bfr[ks] = *(const bf16x8*)(bb + ks * 32);
    f32x4 acc[4] = {};
#pragma unroll
    for (int ks = 0; ks < 8; ++ks) {
      int ae = (ks * 4 + g) * 512 + c * 8;
#pragma unroll
      for (int mt = 0; mt < 4; ++mt) {
        bf16x8 afr = *(const bf16x8*)(xb + xbsw(ae + mt * 128));
        acc[mt] = MFMA16(afr, bfr[ks], acc[mt]);
      }
    }
    float bp = b_proj[ct * 16 + c];
#pragma unroll
    for (int mt = 0; mt < 4; ++mt) {
#pragma unroll
      for (int i = 0; i < 4; ++i) {
        int n = mt * 16 + g * 4 + i;
        if (n < 49) outw[n * 256 + ct * 16 + c] = acc[mt][i] + bp;
      }
    }
  }
}

extern "C" void kernel_launch(void* const* d_in, const int* in_sizes, int n_in,
                              void* d_out, int out_size, void* d_ws, size_t ws_size,
                              hipStream_t stream) {
  const float* x = (const float*)d_in[0];
  const float* mask = (const float*)d_in[1];
  const float* w_qkv = (const float*)d_in[2];
  const float* b_qkv = (const float*)d_in[3];
  const float* w_proj = (const float*)d_in[4];
  const float* b_proj = (const float*)d_in[5];
  const float* bias_table = (const float*)d_in[6];
  const int* rel_index = (const int*)d_in[7];
  float* out = (float*)d_out;
  char* ws = (char*)d_ws;

  (void)in_sizes; (void)n_in; (void)out_size; (void)ws_size;

  hipFuncSetAttribute((const void*)attn_kernel, hipFuncAttributeMaxDynamicSharedMemorySize,
                      LDS_BYTES);

  prep_kernel<<<1103, 256, 0, stream>>>(w_qkv, b_qkv, w_proj, bias_table, rel_index, ws);
  attn_kernel<<<4096, 1024, LDS_BYTES, stream>>>(x, mask, b_proj, ws, out);
}

// Round 4
// 510.723 us; speedup vs baseline: 1.4358x; 1.4358x over previous
//
#include <hip/hip_runtime.h>
#include <hip/hip_bf16.h>

typedef __bf16 bf16;
typedef bf16 bf16x4 __attribute__((ext_vector_type(4)));
typedef bf16 bf16x8 __attribute__((ext_vector_type(8)));
typedef float f32x4 __attribute__((ext_vector_type(4)));

#define MFMA16(a, b, c) __builtin_amdgcn_mfma_f32_16x16x32_bf16((a), (b), (c), 0, 0, 0)

constexpr int kN = 49, kC = 256;
constexpr float kScale = 0.17677669529663687f;  // 1/sqrt(32)

// ---- workspace offsets (bytes) ----
constexpr int WQKV_OFF = 0;        // bf16[768*256]
constexpr int WPROJ_OFF = 393216;  // bf16[256*256]
constexpr int BIAS_OFF = 524288;   // f32[8*49*49]
constexpr int BQKV_OFF = 601120;   // f32[768]

// ---- LDS layout (bytes) ----
// xb: bf16 [32 cc][50 n][8]   = 25600 B  (x staging; later attn-out)
// qk: bf16 [64 oc][50 n][8]   = 51200 B  (Q o<256 scaled, K 256..511; row49=0)
// PT: overlay on qk: per-wave 8192 B  bf16 [4 rt][16 nl][64 m] swizzled
constexpr int XB_OFF = 0;
constexpr int QK_OFF = 25600;
constexpr int QS = 400;  // row-chunk stride in elems (50*8)
constexpr int LDS_BYTES = 76800;

__global__ void prep_kernel(const float* __restrict__ w_qkv, const float* __restrict__ b_qkv,
                            const float* __restrict__ w_proj, const float* __restrict__ bias_table,
                            const int* __restrict__ rel_index, char* __restrict__ ws) {
  int i = blockIdx.x * 256 + threadIdx.x;
  bf16* wqkvb = (bf16*)(ws + WQKV_OFF);
  bf16* wprojb = (bf16*)(ws + WPROJ_OFF);
  float* biasx = (float*)(ws + BIAS_OFF);
  float* bqs = (float*)(ws + BQKV_OFF);
  if (i < 196608) {
    float v = w_qkv[i];
    if (i < 65536) v *= kScale;  // q rows (o<256): fold scale
    wqkvb[i] = (bf16)v;
  } else if (i < 262144) {
    int j = i - 196608;
    wprojb[j] = (bf16)w_proj[j];
  } else if (i < 281352) {
    int j = i - 262144;  // 8*2401
    int h = j / 2401, nm = j - h * 2401;
    biasx[j] = bias_table[rel_index[nm] * 8 + h];
  } else if (i < 282120) {
    int j = i - 281352;
    bqs[j] = b_qkv[j] * (j < 256 ? kScale : 1.0f);
  }
}

__global__ __launch_bounds__(256, 2) void attn_kernel(
    const float* __restrict__ x, const float* __restrict__ mask, const float* __restrict__ b_proj,
    const char* __restrict__ ws, float* __restrict__ out) {
  extern __shared__ char smem[];
  bf16* xb = (bf16*)(smem + XB_OFF);
  bf16* qk = (bf16*)(smem + QK_OFF);

  const bf16* wqkvb = (const bf16*)(ws + WQKV_OFF);
  const bf16* wprojb = (const bf16*)(ws + WPROJ_OFF);
  const float* biasx = (const float*)(ws + BIAS_OFF);
  const float* bqs = (const float*)(ws + BQKV_OFF);

  const int tid = threadIdx.x;
  const int w = blockIdx.x;
  const int lane = tid & 63;
  const int wave = tid >> 6;   // 0..3
  const int g = lane >> 4;     // 16-lane group
  const int c = lane & 15;

  const float* xw = x + (size_t)w * (kN * kC);

  // ---- stage x -> xb bf16, [cc][n<49][8]; no pad rows (garbage paths masked) ----
#pragma unroll
  for (int it = 0; it < 13; ++it) {
    int idx = it * 256 + tid;  // over 49*64 float4 units
    if (idx < 3136) {
      int n = idx >> 6, c4 = (idx & 63) << 2;
      float4 v = ((const float4*)xw)[idx];
      bf16x4 b4;
      b4[0] = (bf16)v.x; b4[1] = (bf16)v.y; b4[2] = (bf16)v.z; b4[3] = (bf16)v.w;
      *(bf16x4*)(xb + ((c4 >> 3) * QS + n * 8 + (c4 & 7))) = b4;
    }
  }
  __syncthreads();

  // ---- sub-GEMM1: Q,K.  D[o][n] = sum_c W[o][c]*X[n][c].  8 o-tiles per wave ----
  for (int t = 0; t < 8; ++t) {
    int ot = wave * 8 + t;
    const bf16* ab = wqkvb + (ot * 16 + c) * 256 + g * 8;  // A row o = l&15, k contig
    bf16x8 afr[8];
#pragma unroll
    for (int ks = 0; ks < 8; ++ks) afr[ks] = *(const bf16x8*)(ab + ks * 32);
    f32x4 acc[4] = {};
#pragma unroll
    for (int ks = 0; ks < 8; ++ks) {
      const bf16* bb = xb + (ks * 4 + g) * QS + c * 8;  // B col n = l&15
#pragma unroll
      for (int nt = 0; nt < 4; ++nt) {
        bf16x8 bfr = *(const bf16x8*)(bb + nt * 128);
        acc[nt] = MFMA16(afr[ks], bfr, acc[nt]);
      }
    }
    int ob = ot * 16 + g * 4;
    float bq0 = bqs[ob], bq1 = bqs[ob + 1], bq2 = bqs[ob + 2], bq3 = bqs[ob + 3];
    int oc = ob >> 3, olow = ob & 7;
#pragma unroll
    for (int nt = 0; nt < 4; ++nt) {
      int n = nt * 16 + c;
      if (n < 50) {
        bool ok = (n < 49);
        bf16x4 pk;
        pk[0] = ok ? (bf16)(acc[nt][0] + bq0) : (bf16)0.f;
        pk[1] = ok ? (bf16)(acc[nt][1] + bq1) : (bf16)0.f;
        pk[2] = ok ? (bf16)(acc[nt][2] + bq2) : (bf16)0.f;
        pk[3] = ok ? (bf16)(acc[nt][3] + bq3) : (bf16)0.f;
        *(bf16x4*)(qk + (oc * QS + n * 8 + olow)) = pk;
      }
    }
  }

  // ---- sub-GEMM2: V -> registers (va) via in-wave shuffle transpose ----
  // wave computes ct = 4w..4w+3  == heads 2w,2w+1 (its own attn heads)
  bf16x8 va[2][2][2];  // [hh][dt][ks]
  for (int t = 0; t < 4; ++t) {
    int ct = wave * 4 + t;
    int o = 512 + ct * 16 + c;
    const bf16* bb = wqkvb + o * 256 + g * 8;
    bf16x8 bfr[8];
#pragma unroll
    for (int ks = 0; ks < 8; ++ks) bfr[ks] = *(const bf16x8*)(bb + ks * 32);
    f32x4 acc[4] = {};
#pragma unroll
    for (int ks = 0; ks < 8; ++ks) {
      const bf16* abL = xb + (ks * 4 + g) * QS + c * 8;
#pragma unroll
      for (int mt = 0; mt < 4; ++mt) {
        bf16x8 afr = *(const bf16x8*)(abL + mt * 128);
        acc[mt] = MFMA16(afr, bfr[ks], acc[mt]);
      }
    }
    float bv = bqs[o];
#pragma unroll
    for (int mt = 0; mt < 4; ++mt) {
      acc[mt][0] += bv; acc[mt][1] += bv; acc[mt][2] += bv; acc[mt][3] += bv;
    }
    // va[hh][dt][ks][j] = V[m=ks*32+g*8+j][d=dt*16+c], from lane ((g&1)*2+(j>>2))*16+c,
    // acc[2ks+(g>>1)][j&3]; mask m>=49 to exact zero.
    int hh = t >> 1, dt = t & 1;
    int base = ((g & 1) * 2) * 16 + c;
#pragma unroll
    for (int ks = 0; ks < 2; ++ks) {
      f32x4 aL = acc[2 * ks], aH = acc[2 * ks + 1];
      float e[8];
#pragma unroll
      for (int i = 0; i < 4; ++i) {
        float xA = __shfl(aL[i], base), yA = __shfl(aH[i], base);
        float xB = __shfl(aL[i], base + 16), yB = __shfl(aH[i], base + 16);
        e[i] = (g < 2) ? xA : yA;
        e[4 + i] = (g < 2) ? xB : yB;
      }
      bf16x8 f;
#pragma unroll
      for (int j = 0; j < 8; ++j) {
        int m = ks * 32 + g * 8 + j;
        f[j] = (m < 49) ? (bf16)e[j] : (bf16)0.f;
      }
      va[hh][dt][ks] = f;
    }
  }
  __syncthreads();  // qk fully written

  // ---- preload BOTH heads' Q/K frags (qk dead after this -> PT overlay ok) ----
  const int h0 = wave * 2;
  bf16x8 qa2[2][4], kb2[2][4];
#pragma unroll
  for (int hh = 0; hh < 2; ++hh) {
    int h = h0 + hh;
#pragma unroll
    for (int rt = 0; rt < 4; ++rt) {
      int n = rt * 16 + c; n = n > 49 ? 49 : n;  // clamp to zero-row
      qa2[hh][rt] = *(const bf16x8*)(qk + ((h * 4 + g) * QS + n * 8));
    }
#pragma unroll
    for (int mt = 0; mt < 4; ++mt) {
      int m = mt * 16 + c; m = m > 49 ? 49 : m;
      kb2[hh][mt] = *(const bf16x8*)(qk + ((32 + h * 4 + g) * QS + m * 8));
    }
  }
  __syncthreads();  // frags in regs; PT overlay on qk region is now safe

  // ---- attention: wave handles heads h0, h0+1 ----
  bf16* ptp = qk + wave * 4096;  // 8192 B per wave, elems: [4 rt][16 nl][64 m] swizzled
  const float* mk = mask + (size_t)w * 2401;

  for (int hh = 0; hh < 2; ++hh) {
    int h = h0 + hh;
    const float* bh = biasx + h * 2401;
    f32x4 s[4][4] = {};
#pragma unroll
    for (int rt = 0; rt < 4; ++rt)
#pragma unroll
      for (int mt = 0; mt < 4; ++mt) s[rt][mt] = MFMA16(qa2[hh][rt], kb2[hh][mt], s[rt][mt]);

#pragma unroll
    for (int rt = 0; rt < 4; ++rt) {
      float pk_[4][4];  // [mt][i]
#pragma unroll
      for (int i = 0; i < 4; ++i) {
        int n = rt * 16 + g * 4 + i;
        bool nok = (n < 49);
        float vals[4];
#pragma unroll
        for (int mt = 0; mt < 4; ++mt) {
          int m = mt * 16 + c;
          float v = -1e30f;
          if (nok && m < 49) v = s[rt][mt][i] + bh[n * 49 + m] + mk[n * 49 + m];
          vals[mt] = v;
        }
        float mx = fmaxf(fmaxf(vals[0], vals[1]), fmaxf(vals[2], vals[3]));
        mx = fmaxf(mx, __shfl_xor(mx, 1));
        mx = fmaxf(mx, __shfl_xor(mx, 2));
        mx = fmaxf(mx, __shfl_xor(mx, 4));
        mx = fmaxf(mx, __shfl_xor(mx, 8));
        float p0 = __expf(vals[0] - mx), p1 = __expf(vals[1] - mx);
        float p2 = __expf(vals[2] - mx), p3 = __expf(vals[3] - mx);
        float sum = p0 + p1 + p2 + p3;
        sum += __shfl_xor(sum, 1);
        sum += __shfl_xor(sum, 2);
        sum += __shfl_xor(sum, 4);
        sum += __shfl_xor(sum, 8);
        float rinv = 1.0f / sum;
        pk_[0][i] = p0 * rinv; pk_[1][i] = p1 * rinv;
        pk_[2][i] = p2 * rinv; pk_[3][i] = p3 * rinv;
      }
      // store P^T swizzled: elem = rt*1024 + nl*64 + (m ^ (g<<4) ^ ((i&1)<<3))
#pragma unroll
      for (int mt = 0; mt < 4; ++mt) {
        int m = mt * 16 + c;
#pragma unroll
        for (int i = 0; i < 4; ++i) {
          int nl = g * 4 + i;
          ptp[rt * 1024 + nl * 64 + (m ^ (g << 4) ^ ((i & 1) << 3))] = (bf16)pk_[mt][i];
        }
      }
    }
    asm volatile("s_waitcnt lgkmcnt(0)" ::: "memory");  // own-wave P visible

    // PV^T: out^T[d][n] = sum_m V^T[d][m] * P^T[m][n]
    f32x4 oacc[2][4] = {};
    const int xr = ((c >> 2) << 4) ^ ((c & 1) << 3);
#pragma unroll
    for (int nt = 0; nt < 4; ++nt) {
      const bf16* pr = ptp + nt * 1024 + c * 64;
      bf16x8 pb0 = *(const bf16x8*)(pr + ((g * 8) ^ xr));
      bf16x8 pb1 = *(const bf16x8*)(pr + ((32 + g * 8) ^ xr));
#pragma unroll
      for (int dt = 0; dt < 2; ++dt) {
        oacc[dt][nt] = MFMA16(va[hh][dt][0], pb0, oacc[dt][nt]);
        oacc[dt][nt] = MFMA16(va[hh][dt][1], pb1, oacc[dt][nt]);
      }
    }
    // attn-out -> xb rows n<49 (xb frag reads done before gemm barrier)
#pragma unroll
    for (int dt = 0; dt < 2; ++dt) {
      int cb = h * 32 + dt * 16 + g * 4;
      int cc = cb >> 3, clow = cb & 7;
#pragma unroll
      for (int nt = 0; nt < 4; ++nt) {
        int n = nt * 16 + c;
        if (n < 49) {
          bf16x4 pk;
          pk[0] = (bf16)oacc[dt][nt][0]; pk[1] = (bf16)oacc[dt][nt][1];
          pk[2] = (bf16)oacc[dt][nt][2]; pk[3] = (bf16)oacc[dt][nt][3];
          *(bf16x4*)(xb + (cc * QS + n * 8 + clow)) = pk;
        }
      }
    }
  }
  __syncthreads();

  // ---- proj: out[n][co] = sum_c ao[n][c]*Wp[co][c] + bp.  4 tiles per wave ----
  float* outw = out + (size_t)w * (kN * kC);
  for (int t = 0; t < 4; ++t) {
    int ct = wave * 4 + t;
    const bf16* bb = wprojb + (ct * 16 + c) * 256 + g * 8;
    bf16x8 bfr[8];
#pragma unroll
    for (int ks = 0; ks < 8; ++ks) bfr[ks] = *(const bf16x8*)(bb + ks * 32);
    f32x4 acc[4] = {};
#pragma unroll
    for (int ks = 0; ks < 8; ++ks) {
      const bf16* abL = xb + (ks * 4 + g) * QS + c * 8;
#pragma unroll
      for (int mt = 0; mt < 4; ++mt) {
        bf16x8 afr = *(const bf16x8*)(abL + mt * 128);
        acc[mt] = MFMA16(afr, bfr[ks], acc[mt]);
      }
    }
    float bp = b_proj[ct * 16 + c];
#pragma unroll
    for (int mt = 0; mt < 4; ++mt) {
#pragma unroll
      for (int i = 0; i < 4; ++i) {
        int n = mt * 16 + g * 4 + i;
        if (n < 49) outw[n * 256 + ct * 16 + c] = acc[mt][i] + bp;
      }
    }
  }
}

extern "C" void kernel_launch(void* const* d_in, const int* in_sizes, int n_in,
                              void* d_out, int out_size, void* d_ws, size_t ws_size,
                              hipStream_t stream) {
  const float* x = (const float*)d_in[0];
  const float* mask = (const float*)d_in[1];
  const float* w_qkv = (const float*)d_in[2];
  const float* b_qkv = (const float*)d_in[3];
  const float* w_proj = (const float*)d_in[4];
  const float* b_proj = (const float*)d_in[5];
  const float* bias_table = (const float*)d_in[6];
  const int* rel_index = (const int*)d_in[7];
  float* out = (float*)d_out;
  char* ws = (char*)d_ws;

  (void)in_sizes; (void)n_in; (void)out_size; (void)ws_size;

  hipFuncSetAttribute((const void*)attn_kernel, hipFuncAttributeMaxDynamicSharedMemorySize,
                      LDS_BYTES);

  prep_kernel<<<1103, 256, 0, stream>>>(w_qkv, b_qkv, w_proj, bias_table, rel_index, ws);
  attn_kernel<<<4096, 256, LDS_BYTES, stream>>>(x, mask, b_proj, ws, out);
}

// Round 5
// 430.971 us; speedup vs baseline: 1.7015x; 1.1851x over previous
//
#include <hip/hip_runtime.h>
#include <hip/hip_bf16.h>

typedef __bf16 bf16;
typedef bf16 bf16x4 __attribute__((ext_vector_type(4)));
typedef bf16 bf16x8 __attribute__((ext_vector_type(8)));
typedef float f32x4 __attribute__((ext_vector_type(4)));

#define MFMA16(a, b, c) __builtin_amdgcn_mfma_f32_16x16x32_bf16((a), (b), (c), 0, 0, 0)

constexpr int kN = 49, kC = 256;
constexpr float kScale = 0.17677669529663687f;  // 1/sqrt(32)

// ---- workspace offsets (bytes) ----
constexpr int WQKV_OFF = 0;        // bf16[768*256]
constexpr int WPROJ_OFF = 393216;  // bf16[256*256]
constexpr int BIAS_OFF = 524288;   // f32[8][49 m][49 n]  (TRANSPOSED bias)
constexpr int BQKV_OFF = 601120;   // f32[768]

// ---- LDS layout (bytes) ----
// xb: bf16 [32 cc][50 n][8]   = 25600 B  (x staging; later attn-out)
// qk: bf16 [64 oc][50 n][8]   = 51200 B  (Q o<256 scaled, K 256..511; row49=0)
//     after attention: f32 outb[49][64 float4] (swizzled), 50176 B
constexpr int XB_OFF = 0;
constexpr int QK_OFF = 25600;
constexpr int QS = 400;  // row-chunk stride in elems (50*8)
constexpr int LDS_BYTES = 76800;

__global__ void prep_kernel(const float* __restrict__ w_qkv, const float* __restrict__ b_qkv,
                            const float* __restrict__ w_proj, const float* __restrict__ bias_table,
                            const int* __restrict__ rel_index, char* __restrict__ ws) {
  int i = blockIdx.x * 256 + threadIdx.x;
  bf16* wqkvb = (bf16*)(ws + WQKV_OFF);
  bf16* wprojb = (bf16*)(ws + WPROJ_OFF);
  float* biasx = (float*)(ws + BIAS_OFF);
  float* bqs = (float*)(ws + BQKV_OFF);
  if (i < 196608) {
    float v = w_qkv[i];
    if (i < 65536) v *= kScale;  // q rows (o<256): fold scale
    wqkvb[i] = (bf16)v;
  } else if (i < 262144) {
    int j = i - 196608;
    wprojb[j] = (bf16)w_proj[j];
  } else if (i < 281352) {
    int j = i - 262144;  // 8*2401, layout [h][m][n]
    int h = j / 2401, nm = j - h * 2401;
    int mm = nm / 49, nn = nm - mm * 49;
    biasx[j] = bias_table[rel_index[nn * 49 + mm] * 8 + h];  // = bias[h][nn][mm]
  } else if (i < 282120) {
    int j = i - 281352;
    bqs[j] = b_qkv[j] * (j < 256 ? kScale : 1.0f);
  }
}

__global__ __launch_bounds__(256, 2) void attn_kernel(
    const float* __restrict__ x, const float* __restrict__ mask, const float* __restrict__ b_proj,
    const char* __restrict__ ws, float* __restrict__ out) {
  extern __shared__ char smem[];
  bf16* xb = (bf16*)(smem + XB_OFF);
  bf16* qk = (bf16*)(smem + QK_OFF);
  float* outf = (float*)(smem + QK_OFF);  // overlays qk after attention

  const bf16* wqkvb = (const bf16*)(ws + WQKV_OFF);
  const bf16* wprojb = (const bf16*)(ws + WPROJ_OFF);
  const float* biasx = (const float*)(ws + BIAS_OFF);
  const float* bqs = (const float*)(ws + BQKV_OFF);

  const int tid = threadIdx.x;
  const int w = blockIdx.x;
  const int lane = tid & 63;
  const int wave = tid >> 6;   // 0..3
  const int g = lane >> 4;     // 16-lane group
  const int c = lane & 15;

  const float* xw = x + (size_t)w * (kN * kC);

  // ---- stage x -> xb bf16, [cc][n<49][8] ----
#pragma unroll
  for (int it = 0; it < 13; ++it) {
    int idx = it * 256 + tid;  // over 49*64 float4 units
    if (idx < 3136) {
      int n = idx >> 6, c4 = (idx & 63) << 2;
      float4 v = ((const float4*)xw)[idx];
      bf16x4 b4;
      b4[0] = (bf16)v.x; b4[1] = (bf16)v.y; b4[2] = (bf16)v.z; b4[3] = (bf16)v.w;
      *(bf16x4*)(xb + ((c4 >> 3) * QS + n * 8 + (c4 & 7))) = b4;
    }
  }
  __syncthreads();

  // ---- sub-GEMM1: Q,K.  D[o][n] = sum_c W[o][c]*X[n][c].  8 o-tiles per wave ----
  for (int t = 0; t < 8; ++t) {
    int ot = wave * 8 + t;
    const bf16* ab = wqkvb + (ot * 16 + c) * 256 + g * 8;  // A row o = l&15, k contig
    bf16x8 afr[8];
#pragma unroll
    for (int ks = 0; ks < 8; ++ks) afr[ks] = *(const bf16x8*)(ab + ks * 32);
    f32x4 acc[4] = {};
#pragma unroll
    for (int ks = 0; ks < 8; ++ks) {
      const bf16* bb = xb + (ks * 4 + g) * QS + c * 8;  // B col n = l&15
#pragma unroll
      for (int nt = 0; nt < 4; ++nt) {
        bf16x8 bfr = *(const bf16x8*)(bb + nt * 128);
        acc[nt] = MFMA16(afr[ks], bfr, acc[nt]);
      }
    }
    int ob = ot * 16 + g * 4;
    float bq0 = bqs[ob], bq1 = bqs[ob + 1], bq2 = bqs[ob + 2], bq3 = bqs[ob + 3];
    int oc = ob >> 3, olow = ob & 7;
#pragma unroll
    for (int nt = 0; nt < 4; ++nt) {
      int n = nt * 16 + c;
      if (n < 50) {
        bool ok = (n < 49);
        bf16x4 pk;
        pk[0] = ok ? (bf16)(acc[nt][0] + bq0) : (bf16)0.f;
        pk[1] = ok ? (bf16)(acc[nt][1] + bq1) : (bf16)0.f;
        pk[2] = ok ? (bf16)(acc[nt][2] + bq2) : (bf16)0.f;
        pk[3] = ok ? (bf16)(acc[nt][3] + bq3) : (bf16)0.f;
        *(bf16x4*)(qk + (oc * QS + n * 8 + olow)) = pk;
      }
    }
  }

  // ---- sub-GEMM2: V -> registers (va) via in-wave shuffle transpose ----
  bf16x8 va[2][2][2];  // [hh][dt][ks]
  for (int t = 0; t < 4; ++t) {
    int ct = wave * 4 + t;
    int o = 512 + ct * 16 + c;
    const bf16* bb = wqkvb + o * 256 + g * 8;
    bf16x8 bfr[8];
#pragma unroll
    for (int ks = 0; ks < 8; ++ks) bfr[ks] = *(const bf16x8*)(bb + ks * 32);
    f32x4 acc[4] = {};
#pragma unroll
    for (int ks = 0; ks < 8; ++ks) {
      const bf16* abL = xb + (ks * 4 + g) * QS + c * 8;
#pragma unroll
      for (int mt = 0; mt < 4; ++mt) {
        bf16x8 afr = *(const bf16x8*)(abL + mt * 128);
        acc[mt] = MFMA16(afr, bfr[ks], acc[mt]);
      }
    }
    float bv = bqs[o];
#pragma unroll
    for (int mt = 0; mt < 4; ++mt) {
      acc[mt][0] += bv; acc[mt][1] += bv; acc[mt][2] += bv; acc[mt][3] += bv;
    }
    // va[hh][dt][ks][j] = V[m=ks*32+g*8+j][d=dt*16+c]
    int hh = t >> 1, dt = t & 1;
    int base = ((g & 1) * 2) * 16 + c;
#pragma unroll
    for (int ks = 0; ks < 2; ++ks) {
      f32x4 aL = acc[2 * ks], aH = acc[2 * ks + 1];
      float e[8];
#pragma unroll
      for (int i = 0; i < 4; ++i) {
        float xA = __shfl(aL[i], base), yA = __shfl(aH[i], base);
        float xB = __shfl(aL[i], base + 16), yB = __shfl(aH[i], base + 16);
        e[i] = (g < 2) ? xA : yA;
        e[4 + i] = (g < 2) ? xB : yB;
      }
      bf16x8 f;
#pragma unroll
      for (int j = 0; j < 8; ++j) {
        int m = ks * 32 + g * 8 + j;
        f[j] = (m < 49) ? (bf16)e[j] : (bf16)0.f;
      }
      va[hh][dt][ks] = f;
    }
  }
  __syncthreads();  // qk fully written; xb x-content dead after this phase

  // ---- attention (S^T form): wave handles heads 2w, 2w+1 ----
  const int h0 = wave * 2;
  const float* mk = mask + (size_t)w * 2401;

#pragma unroll
  for (int hh = 0; hh < 2; ++hh) {
    int h = h0 + hh;
    const float* bhT = biasx + h * 2401;  // [m][n]

    // Q/K fragments for this head (row-clamp to zero-row 49)
    bf16x8 qa[4], kb[4];
#pragma unroll
    for (int rt = 0; rt < 4; ++rt) {
      int n = rt * 16 + c; n = n > 49 ? 49 : n;
      qa[rt] = *(const bf16x8*)(qk + ((h * 4 + g) * QS + n * 8));
    }
#pragma unroll
    for (int mt = 0; mt < 4; ++mt) {
      int m = mt * 16 + c; m = m > 49 ? 49 : m;
      kb[mt] = *(const bf16x8*)(qk + ((32 + h * 4 + g) * QS + m * 8));
    }

    // S^T[m][n]: rows m (A=K), cols n (B=Q)
    f32x4 s[4][4] = {};
#pragma unroll
    for (int mt = 0; mt < 4; ++mt)
#pragma unroll
      for (int nt = 0; nt < 4; ++nt) s[mt][nt] = MFMA16(kb[mt], qa[nt], s[mt][nt]);

    f32x4 oacc[2][4] = {};
#pragma unroll
    for (int nt = 0; nt < 4; ++nt) {
      int n = nt * 16 + c;
      int nc = n > 48 ? 48 : n;
      bool nok = (n < 49);
      // softmax over m for column n (16 in-lane values + reduce over g)
      float vals[4][4];
#pragma unroll
      for (int mt = 0; mt < 4; ++mt)
#pragma unroll
        for (int i = 0; i < 4; ++i) {
          int m = mt * 16 + g * 4 + i;
          int mc2 = m > 48 ? 48 : m;
          float bv = bhT[mc2 * 49 + nc];      // contiguous in c
          float mv = mk[nc * 49 + mc2];       // stride-49 gather (L1-hot)
          vals[mt][i] = (nok && m < 49) ? (s[mt][nt][i] + bv + mv) : -1e30f;
        }
      float mx = vals[0][0];
#pragma unroll
      for (int mt = 0; mt < 4; ++mt)
#pragma unroll
        for (int i = 0; i < 4; ++i) mx = fmaxf(mx, vals[mt][i]);
      mx = fmaxf(mx, __shfl_xor(mx, 16));
      mx = fmaxf(mx, __shfl_xor(mx, 32));
      float p_[4][4];
      float sum = 0.f;
#pragma unroll
      for (int mt = 0; mt < 4; ++mt)
#pragma unroll
        for (int i = 0; i < 4; ++i) {
          float pv = __expf(vals[mt][i] - mx);
          p_[mt][i] = pv;
          sum += pv;
        }
      sum += __shfl_xor(sum, 16);
      sum += __shfl_xor(sum, 32);
      float rinv = nok ? (1.0f / sum) : 0.0f;
#pragma unroll
      for (int mt = 0; mt < 4; ++mt)
#pragma unroll
        for (int i = 0; i < 4; ++i) p_[mt][i] *= rinv;

      // pb[ks][j] = P^T[m=ks*32+g*8+j][n] via register shuffle (no LDS)
#pragma unroll
      for (int ks = 0; ks < 2; ++ks) {
        float e[8];
#pragma unroll
        for (int j = 0; j < 8; ++j) {
          int src = ((g & 1) * 2 + (j >> 2)) * 16 + c;
          float vA = __shfl(p_[2 * ks][j & 3], src);
          float vB = __shfl(p_[2 * ks + 1][j & 3], src);
          e[j] = (g < 2) ? vA : vB;
        }
        bf16x8 f;
#pragma unroll
        for (int j = 0; j < 8; ++j) f[j] = (bf16)e[j];
#pragma unroll
        for (int dt = 0; dt < 2; ++dt) oacc[dt][nt] = MFMA16(va[hh][dt][ks], f, oacc[dt][nt]);
      }
    }

    // attn-out -> xb rows n<49
#pragma unroll
    for (int dt = 0; dt < 2; ++dt) {
      int cb = h * 32 + dt * 16 + g * 4;
      int cc = cb >> 3, clow = cb & 7;
#pragma unroll
      for (int nt = 0; nt < 4; ++nt) {
        int n = nt * 16 + c;
        if (n < 49) {
          bf16x4 pk;
          pk[0] = (bf16)oacc[dt][nt][0]; pk[1] = (bf16)oacc[dt][nt][1];
          pk[2] = (bf16)oacc[dt][nt][2]; pk[3] = (bf16)oacc[dt][nt][3];
          *(bf16x4*)(xb + (cc * QS + n * 8 + clow)) = pk;
        }
      }
    }
  }
  __syncthreads();  // attn-out complete; qk dead -> outf overlay safe

  // ---- proj: out[n][co] = sum_c ao[n][c]*Wp[co][c] + bp -> LDS outf (swizzled) ----
  for (int t = 0; t < 4; ++t) {
    int ct = wave * 4 + t;
    const bf16* bb = wprojb + (ct * 16 + c) * 256 + g * 8;
    bf16x8 bfr[8];
#pragma unroll
    for (int ks = 0; ks < 8; ++ks) bfr[ks] = *(const bf16x8*)(bb + ks * 32);
    f32x4 acc[4] = {};
#pragma unroll
    for (int ks = 0; ks < 8; ++ks) {
      const bf16* abL = xb + (ks * 4 + g) * QS + c * 8;
#pragma unroll
      for (int mt = 0; mt < 4; ++mt) {
        bf16x8 afr = *(const bf16x8*)(abL + mt * 128);
        acc[mt] = MFMA16(afr, bfr[ks], acc[mt]);
      }
    }
    float bp = b_proj[ct * 16 + c];
    int co = ct * 16 + c, q = co >> 2, c3 = co & 3;
#pragma unroll
    for (int mt = 0; mt < 4; ++mt) {
#pragma unroll
      for (int i = 0; i < 4; ++i) {
        int n = mt * 16 + g * 4 + i;
        if (n < 49) outf[n * 256 + ((q ^ (n & 15)) << 2) + c3] = acc[mt][i] + bp;
      }
    }
  }
  __syncthreads();

  // ---- coalesced copy LDS -> global (full float4 rows) ----
  float4* outw4 = (float4*)(out + (size_t)w * (kN * kC));
  const float4* outf4 = (const float4*)outf;
#pragma unroll
  for (int it = 0; it < 13; ++it) {
    int f = it * 256 + tid;
    if (f < 3136) {
      int n = f >> 6, q = f & 63;
      outw4[f] = outf4[n * 64 + (q ^ (n & 15))];
    }
  }
}

extern "C" void kernel_launch(void* const* d_in, const int* in_sizes, int n_in,
                              void* d_out, int out_size, void* d_ws, size_t ws_size,
                              hipStream_t stream) {
  const float* x = (const float*)d_in[0];
  const float* mask = (const float*)d_in[1];
  const float* w_qkv = (const float*)d_in[2];
  const float* b_qkv = (const float*)d_in[3];
  const float* w_proj = (const float*)d_in[4];
  const float* b_proj = (const float*)d_in[5];
  const float* bias_table = (const float*)d_in[6];
  const int* rel_index = (const int*)d_in[7];
  float* out = (float*)d_out;
  char* ws = (char*)d_ws;

  (void)in_sizes; (void)n_in; (void)out_size; (void)ws_size;

  hipFuncSetAttribute((const void*)attn_kernel, hipFuncAttributeMaxDynamicSharedMemorySize,
                      LDS_BYTES);

  prep_kernel<<<1103, 256, 0, stream>>>(w_qkv, b_qkv, w_proj, bias_table, rel_index, ws);
  attn_kernel<<<4096, 256, LDS_BYTES, stream>>>(x, mask, b_proj, ws, out);
}